// Round 4
// baseline (905.021 us; speedup 1.0000x reference)
//
#include <hip/hip_runtime.h>

typedef unsigned int uint32;
typedef unsigned int v4u __attribute__((ext_vector_type(4)));

__device__ __forceinline__ uint32 nib_of(v4u b) {
    // pulse word is exactly 0x3F800000 (1.0f) or 0x00000000; test bit 29.
    return ((b.x >> 26) & 8u) | ((b.y >> 27) & 4u) |
           ((b.z >> 28) & 2u) | ((b.w >> 29) & 1u);
}

__device__ __forceinline__ uint32 butterfly_or(uint32 u) {
    // OR across the 8-lane group: every lane ends with the full 32-bit word
    u |= __shfl_xor(u, 1);
    u |= __shfl_xor(u, 2);
    u |= __shfl_xor(u, 4);
    return u;
}

__device__ __forceinline__ uint32 tanh_bits(uint32 u) {
    // exact FP64 op sequence of the reference
    double v = (double)__uint_as_float(u);
    double e2x = exp(2.0 * v);
    double t64 = (e2x - 1.0) / (e2x + 1.0);
    return __float_as_uint((float)t64);
}

__device__ __forceinline__ v4u expand_nibble(uint32 ru, int shift) {
    uint32 onib = (ru >> shift) & 0xFu;
    v4u o;
    o.x = (onib & 8u) ? 0x3F800000u : 0u;
    o.y = (onib & 4u) ? 0x3F800000u : 0u;
    o.z = (onib & 2u) ? 0x3F800000u : 0u;
    o.w = (onib & 1u) ? 0x3F800000u : 0u;
    return o;
}

__global__ __launch_bounds__(256) void
spike_tanh_kernel(const v4u* __restrict__ in, v4u* __restrict__ out,
                  int n_vec4, int n_main) {
    const int stride = gridDim.x * blockDim.x;       // v4u elements per sweep
    const int shift  = 4 * (7 - (threadIdx.x & 7));  // MSB-first nibble of this lane
    int i = blockIdx.x * blockDim.x + threadIdx.x;

    // main loop: 4-deep, no bounds checks (n_main is a multiple of 4*stride)
    for (; i < n_main; i += 4 * stride) {
        // all 4 independent loads issued up front (4x MLP)
        v4u a0 = in[i];
        v4u a1 = in[i + stride];
        v4u a2 = in[i + 2 * stride];
        v4u a3 = in[i + 3 * stride];

        uint32 u0 = butterfly_or(nib_of(a0) << shift);
        uint32 u1 = butterfly_or(nib_of(a1) << shift);
        uint32 u2 = butterfly_or(nib_of(a2) << shift);
        uint32 u3 = butterfly_or(nib_of(a3) << shift);

        uint32 r0 = tanh_bits(u0);
        uint32 r1 = tanh_bits(u1);
        uint32 r2 = tanh_bits(u2);
        uint32 r3 = tanh_bits(u3);

        __builtin_nontemporal_store(expand_nibble(r0, shift), out + i);
        __builtin_nontemporal_store(expand_nibble(r1, shift), out + i + stride);
        __builtin_nontemporal_store(expand_nibble(r2, shift), out + i + 2 * stride);
        __builtin_nontemporal_store(expand_nibble(r3, shift), out + i + 3 * stride);
    }
    // generic tail (empty for N = 4M scalars with grid 2048x256)
    for (; i < n_vec4; i += stride) {
        v4u a = in[i];
        uint32 r = tanh_bits(butterfly_or(nib_of(a) << shift));
        __builtin_nontemporal_store(expand_nibble(r, shift), out + i);
    }
}

extern "C" void kernel_launch(void* const* d_in, const int* in_sizes, int n_in,
                              void* d_out, int out_size, void* d_ws, size_t ws_size,
                              hipStream_t stream) {
    (void)n_in; (void)d_ws; (void)ws_size; (void)out_size;
    const int n_vec4 = in_sizes[0] / 4;             // 33,554,432 uint4s
    const v4u* in  = (const v4u*)d_in[0];
    v4u*       out = (v4u*)d_out;

    const int block = 256;
    long grid_l = ((long)n_vec4 + block - 1) / block;
    int grid = grid_l > 2048 ? 2048 : (int)grid_l;
    const int stride = grid * block;                // 524,288
    const int chunk  = 4 * stride;
    const int n_main = (n_vec4 / chunk) * chunk;    // == n_vec4 here (64 sweeps)
    spike_tanh_kernel<<<grid, block, 0, stream>>>(in, out, n_vec4, n_main);
}

// Round 6
// 866.044 us; speedup vs baseline: 1.0450x; 1.0450x over previous
//
#include <hip/hip_runtime.h>

typedef unsigned int uint32;
typedef unsigned long long uint64;
typedef unsigned int v4u __attribute__((ext_vector_type(4)));

// spread bits of an 8-bit value to every 4th bit: bit p -> bit 4p
__device__ __forceinline__ uint32 spread4(uint32 t) {
    t = (t | (t << 12)) & 0x000F000Fu;
    t = (t | (t << 6))  & 0x03030303u;
    t = (t | (t << 3))  & 0x11111111u;
    return t;
}

__device__ __forceinline__ uint32 brev8(uint32 b) {
    return __brev(b) >> 24;  // bit-reverse within the low byte
}

// Rebuild the scalar's IEEE-754 word from wave-wide ballots (no shuffles/LDS).
// Lane 8g+pos holds pulse words j=4*pos..4*pos+3 (MSB-first) in x,y,z,w.
__device__ __forceinline__ uint32 assemble_ballot(v4u b, uint32 sh8) {
    uint64 Bx = __ballot(b.x != 0u);
    uint64 By = __ballot(b.y != 0u);
    uint64 Bz = __ballot(b.z != 0u);
    uint64 Bw = __ballot(b.w != 0u);
    uint32 rx = brev8((uint32)(Bx >> sh8) & 0xFFu);
    uint32 ry = brev8((uint32)(By >> sh8) & 0xFFu);
    uint32 rz = brev8((uint32)(Bz >> sh8) & 0xFFu);
    uint32 rw = brev8((uint32)(Bw >> sh8) & 0xFFu);
    // u bit (4*pos'+c') with pos'=7-pos, c'=3-c  ==  word j=4pos+c, MSB first
    return (spread4(rx) << 3) | (spread4(ry) << 2) | (spread4(rz) << 1) | spread4(rw);
}

__device__ __forceinline__ uint32 tanh_bits(uint32 u) {
    // exact FP64 op sequence of the reference
    double v = (double)__uint_as_float(u);
    double e2x = exp(2.0 * v);
    double t64 = (e2x - 1.0) / (e2x + 1.0);
    return __float_as_uint((float)t64);
}

__device__ __forceinline__ v4u expand_nibble(uint32 ru, int shift) {
    uint32 onib = (ru >> shift) & 0xFu;
    v4u o;
    o.x = (onib & 8u) ? 0x3F800000u : 0u;
    o.y = (onib & 4u) ? 0x3F800000u : 0u;
    o.z = (onib & 2u) ? 0x3F800000u : 0u;
    o.w = (onib & 1u) ? 0x3F800000u : 0u;
    return o;
}

__global__ __launch_bounds__(256) void
spike_tanh_kernel(const v4u* __restrict__ in, v4u* __restrict__ out,
                  int n_vec4, int n_main) {
    const int stride = gridDim.x * blockDim.x;        // v4u elements per sweep
    const int lane   = threadIdx.x & 63;
    const uint32 sh8 = (uint32)(lane & ~7);           // 8*group: this lane's byte in ballots
    const int shift  = 4 * (7 - (lane & 7));          // MSB-first nibble of this lane
    int i = blockIdx.x * blockDim.x + threadIdx.x;

    // main loop: 2-deep, branch-free (n_main is a multiple of 2*stride)
    for (; i < n_main; i += 2 * stride) {
        const int i1 = i + stride;
        v4u a0 = __builtin_nontemporal_load(in + i);
        v4u a1 = __builtin_nontemporal_load(in + i1);

        uint32 u0 = assemble_ballot(a0, sh8);
        uint32 u1 = assemble_ballot(a1, sh8);

        uint32 r0 = tanh_bits(u0);
        uint32 r1 = tanh_bits(u1);

        __builtin_nontemporal_store(expand_nibble(r0, shift), out + i);
        __builtin_nontemporal_store(expand_nibble(r1, shift), out + i1);
    }
    // generic tail (empty for N=4M scalars with grid 2048x256); n_vec4 and
    // stride are multiples of 8, so whole 8-lane groups exit together and
    // ballot semantics within a group stay intact.
    for (; i < n_vec4; i += stride) {
        v4u a = __builtin_nontemporal_load(in + i);
        uint32 r = tanh_bits(assemble_ballot(a, sh8));
        __builtin_nontemporal_store(expand_nibble(r, shift), out + i);
    }
}

extern "C" void kernel_launch(void* const* d_in, const int* in_sizes, int n_in,
                              void* d_out, int out_size, void* d_ws, size_t ws_size,
                              hipStream_t stream) {
    (void)n_in; (void)d_ws; (void)ws_size; (void)out_size;
    const int n_vec4 = in_sizes[0] / 4;             // 33,554,432 uint4s
    const v4u* in  = (const v4u*)d_in[0];
    v4u*       out = (v4u*)d_out;

    const int block = 256;
    long grid_l = ((long)n_vec4 + block - 1) / block;
    int grid = grid_l > 2048 ? 2048 : (int)grid_l;
    const int stride = grid * block;                // 524,288
    const int chunk  = 2 * stride;
    const int n_main = (n_vec4 / chunk) * chunk;    // == n_vec4 here
    spike_tanh_kernel<<<grid, block, 0, stream>>>(in, out, n_vec4, n_main);
}